// Round 4
// baseline (12643.391 us; speedup 1.0000x reference)
//
#include <hip/hip_runtime.h>
#include <math.h>

#define KD 128
#define ROWS 32      // rows (nodes or edges) per block
#define BT 256       // ROWS * 8 threads; 8 threads cover 128 cols (16 each)
#define LN_EPS 1e-5f

// ---------- helpers ----------

__device__ __forceinline__ float red8(float v) {
    // sum across the 8 consecutive lanes that share one row
    v += __shfl_xor(v, 1);
    v += __shfl_xor(v, 2);
    v += __shfl_xor(v, 4);
    return v;
}

__device__ __forceinline__ float sigmoidf_(float x) {
    return 1.0f / (1.0f + __expf(-x));
}

#define FMA16(XK, WA, WB, WC, WD)                                   \
    acc[0]  = fmaf(XK, WA.x, acc[0]);  acc[1]  = fmaf(XK, WA.y, acc[1]);  \
    acc[2]  = fmaf(XK, WA.z, acc[2]);  acc[3]  = fmaf(XK, WA.w, acc[3]);  \
    acc[4]  = fmaf(XK, WB.x, acc[4]);  acc[5]  = fmaf(XK, WB.y, acc[5]);  \
    acc[6]  = fmaf(XK, WB.z, acc[6]);  acc[7]  = fmaf(XK, WB.w, acc[7]);  \
    acc[8]  = fmaf(XK, WC.x, acc[8]);  acc[9]  = fmaf(XK, WC.y, acc[9]);  \
    acc[10] = fmaf(XK, WC.z, acc[10]); acc[11] = fmaf(XK, WC.w, acc[11]); \
    acc[12] = fmaf(XK, WD.x, acc[12]); acc[13] = fmaf(XK, WD.y, acc[13]); \
    acc[14] = fmaf(XK, WD.z, acc[14]); acc[15] = fmaf(XK, WD.w, acc[15]);

// [ROWS x KD] tile (LDS) @ W[KD x KD] -> 16 outputs for (rl, d0..d0+15)
__device__ __forceinline__ void tile_gemm(const float (*tile)[KD + 4],
                                          const float* __restrict__ W,
                                          int rl, int d0, float acc[16]) {
#pragma unroll
    for (int j = 0; j < 16; ++j) acc[j] = 0.0f;
#pragma unroll 2
    for (int k4 = 0; k4 < KD / 4; ++k4) {
        float4 xk4 = *(const float4*)(&tile[rl][k4 * 4]);
        const float* Wr = W + (k4 * 4) * KD + d0;
        {
            float xk = xk4.x;
            const float4* wp = (const float4*)(Wr);
            float4 wa = wp[0], wb = wp[1], wc = wp[2], wd = wp[3];
            FMA16(xk, wa, wb, wc, wd);
        }
        {
            float xk = xk4.y;
            const float4* wp = (const float4*)(Wr + KD);
            float4 wa = wp[0], wb = wp[1], wc = wp[2], wd = wp[3];
            FMA16(xk, wa, wb, wc, wd);
        }
        {
            float xk = xk4.z;
            const float4* wp = (const float4*)(Wr + 2 * KD);
            float4 wa = wp[0], wb = wp[1], wc = wp[2], wd = wp[3];
            FMA16(xk, wa, wb, wc, wd);
        }
        {
            float xk = xk4.w;
            const float4* wp = (const float4*)(Wr + 3 * KD);
            float4 wa = wp[0], wb = wp[1], wc = wp[2], wd = wp[3];
            FMA16(xk, wa, wb, wc, wd);
        }
    }
}

// coalesced stage of a [ROWS x KD] tile into LDS; zero-fills OOB rows
__device__ __forceinline__ void stage_tile(const float* __restrict__ Xg, int rowBase,
                                           int nRows, float (*tile)[KD + 4], int t) {
    int r = t >> 3;
    int c = (t & 7) * 16;
    int gr = rowBase + r;
    float4 v0, v1, v2, v3;
    if (gr < nRows) {
        const float4* p = (const float4*)(Xg + (size_t)gr * KD + c);
        v0 = p[0]; v1 = p[1]; v2 = p[2]; v3 = p[3];
    } else {
        v0 = v1 = v2 = v3 = make_float4(0.f, 0.f, 0.f, 0.f);
    }
    float4* q = (float4*)(&tile[r][c]);
    q[0] = v0; q[1] = v1; q[2] = v2; q[3] = v3;
}

__device__ __forceinline__ void store_bias(float* __restrict__ O, const float* __restrict__ b,
                                           int gr, int d0, const float acc[16], int nRows) {
    if (gr >= nRows) return;
    const float4* bp = (const float4*)(b + d0);
    float4* op = (float4*)(O + (size_t)gr * KD + d0);
#pragma unroll
    for (int q = 0; q < 4; ++q) {
        float4 bb = bp[q];
        float4 o;
        o.x = acc[q * 4 + 0] + bb.x;
        o.y = acc[q * 4 + 1] + bb.y;
        o.z = acc[q * 4 + 2] + bb.z;
        o.w = acc[q * 4 + 3] + bb.w;
        op[q] = o;
    }
}

// ---------- kernel 1: three node GEMMs sharing one X tile ----------
// e_src = X@W_src_gate+b ; e_dst = X@W_dst_gate+b ; Bh = X@W_dst_update+b
__global__ void __launch_bounds__(BT)
node_gemm3(const float* __restrict__ X,
           const float* __restrict__ W0, const float* __restrict__ b0,
           const float* __restrict__ W1, const float* __restrict__ b1,
           const float* __restrict__ W2, const float* __restrict__ b2,
           float* __restrict__ O0, float* __restrict__ O1,
           float* __restrict__ O2, int N) {
    __shared__ float tile[ROWS][KD + 4];
    int t = threadIdx.x;
    int rowBase = blockIdx.x * ROWS;
    stage_tile(X, rowBase, N, tile, t);
    __syncthreads();
    int rl = t >> 3, d0 = (t & 7) * 16;
    int gr = rowBase + rl;
    float acc[16];
    tile_gemm(tile, W0, rl, d0, acc);
    store_bias(O0, b0, gr, d0, acc, N);
    tile_gemm(tile, W1, rl, d0, acc);
    store_bias(O1, b1, gr, d0, acc, N);
    tile_gemm(tile, W2, rl, d0, acc);
    store_bias(O2, b2, gr, d0, acc, N);
}

// ---------- kernel 2: fused edge pipeline ----------
// m = EF@W + b + e_src[src] + e_dst[dst]; sigma = sigmoid(m)
// atomic scatter: ssh[dst] += Bh[src]*sigma ; ss[dst] += sigma
// y = EF + silu(LN(m)) written straight to output. m never hits HBM.
__global__ void __launch_bounds__(BT)
edge_fused(const float* __restrict__ EF, const int* __restrict__ src,
           const int* __restrict__ dst,
           const float* __restrict__ W, const float* __restrict__ bW,
           const float* __restrict__ Esrc, const float* __restrict__ Edst,
           const float* __restrict__ Bh,
           const float* __restrict__ g, const float* __restrict__ beta,
           float* __restrict__ ssh, float* __restrict__ ssum,
           float* __restrict__ yout, int E) {
    __shared__ float tile[ROWS][KD + 4];
    int t = threadIdx.x;
    int eBase = blockIdx.x * ROWS;
    stage_tile(EF, eBase, E, tile, t);
    __syncthreads();
    int rl = t >> 3, d0 = (t & 7) * 16;
    int e = eBase + rl;
    bool valid = e < E;

    float acc[16];
    tile_gemm(tile, W, rl, d0, acc);

    int s = 0, dd = 0;
    if (valid) { s = src[e]; dd = dst[e]; }

    const float4* ps = (const float4*)(Esrc + (size_t)s * KD + d0);
    const float4* pd = (const float4*)(Edst + (size_t)dd * KD + d0);
    const float4* pb = (const float4*)(bW + d0);
#pragma unroll
    for (int q = 0; q < 4; ++q) {
        float4 a = ps[q], bq = pd[q], c = pb[q];
        acc[q * 4 + 0] += a.x + bq.x + c.x;
        acc[q * 4 + 1] += a.y + bq.y + c.y;
        acc[q * 4 + 2] += a.z + bq.z + c.z;
        acc[q * 4 + 3] += a.w + bq.w + c.w;
    }

    float sg[16];
#pragma unroll
    for (int j = 0; j < 16; ++j) sg[j] = sigmoidf_(acc[j]);

    if (valid) {
        const float4* pbh = (const float4*)(Bh + (size_t)s * KD + d0);
        float* pssh = ssh + (size_t)dd * KD + d0;
        float* pss = ssum + (size_t)dd * KD + d0;
#pragma unroll
        for (int q = 0; q < 4; ++q) {
            float4 bh = pbh[q];
            atomicAdd(pssh + q * 4 + 0, bh.x * sg[q * 4 + 0]);
            atomicAdd(pssh + q * 4 + 1, bh.y * sg[q * 4 + 1]);
            atomicAdd(pssh + q * 4 + 2, bh.z * sg[q * 4 + 2]);
            atomicAdd(pssh + q * 4 + 3, bh.w * sg[q * 4 + 3]);
            atomicAdd(pss + q * 4 + 0, sg[q * 4 + 0]);
            atomicAdd(pss + q * 4 + 1, sg[q * 4 + 1]);
            atomicAdd(pss + q * 4 + 2, sg[q * 4 + 2]);
            atomicAdd(pss + q * 4 + 3, sg[q * 4 + 3]);
        }
    }

    // LayerNorm of m over the 128-wide row (two-pass, in registers)
    float sum = 0.f;
#pragma unroll
    for (int j = 0; j < 16; ++j) sum += acc[j];
    sum = red8(sum);
    float mu = sum * (1.0f / KD);
    float vs = 0.f;
#pragma unroll
    for (int j = 0; j < 16; ++j) { float dlt = acc[j] - mu; vs = fmaf(dlt, dlt, vs); }
    vs = red8(vs);
    float rstd = rsqrtf(vs * (1.0f / KD) + LN_EPS);

    if (valid) {
        const float4* pg = (const float4*)(g + d0);
        const float4* pbe = (const float4*)(beta + d0);
        float4* op = (float4*)(yout + (size_t)e * KD + d0);
#pragma unroll
        for (int q = 0; q < 4; ++q) {
            float4 gq = pg[q], bq = pbe[q];
            const float4 efq = *(const float4*)(&tile[rl][d0 + q * 4]);
            float4 o;
            {
                float ln = (acc[q * 4 + 0] - mu) * rstd * gq.x + bq.x;
                o.x = efq.x + ln * sigmoidf_(ln);
            }
            {
                float ln = (acc[q * 4 + 1] - mu) * rstd * gq.y + bq.y;
                o.y = efq.y + ln * sigmoidf_(ln);
            }
            {
                float ln = (acc[q * 4 + 2] - mu) * rstd * gq.z + bq.z;
                o.z = efq.z + ln * sigmoidf_(ln);
            }
            {
                float ln = (acc[q * 4 + 3] - mu) * rstd * gq.w + bq.w;
                o.w = efq.w + ln * sigmoidf_(ln);
            }
            op[q] = o;
        }
    }
}

// ---------- kernel 3: node finalize (x_lin GEMM recomputed here) ----------
// x = NF@W_src_update + b + ssh/(ssum+1e-6); out = NF + silu(LN(x))
__global__ void __launch_bounds__(BT)
node_finalize(const float* __restrict__ NF,
              const float* __restrict__ W, const float* __restrict__ bW,
              const float* __restrict__ ssh, const float* __restrict__ ssum,
              const float* __restrict__ g, const float* __restrict__ beta,
              float* __restrict__ out, int N) {
    __shared__ float tile[ROWS][KD + 4];
    int t = threadIdx.x;
    int rowBase = blockIdx.x * ROWS;
    stage_tile(NF, rowBase, N, tile, t);
    __syncthreads();
    int rl = t >> 3, d0 = (t & 7) * 16;
    int r = rowBase + rl;

    float x[16];
    tile_gemm(tile, W, rl, d0, x);   // x = NF@W  (bias added below)

    bool valid = r < N;
    int rr = valid ? r : 0;
    const float4* pb = (const float4*)(bW + d0);
    const float4* pn = (const float4*)(ssh + (size_t)rr * KD + d0);
    const float4* pq = (const float4*)(ssum + (size_t)rr * KD + d0);
#pragma unroll
    for (int q = 0; q < 4; ++q) {
        float4 bb = pb[q], nu = pn[q], de = pq[q];
        x[q * 4 + 0] += bb.x + nu.x / (de.x + 1e-6f);
        x[q * 4 + 1] += bb.y + nu.y / (de.y + 1e-6f);
        x[q * 4 + 2] += bb.z + nu.z / (de.z + 1e-6f);
        x[q * 4 + 3] += bb.w + nu.w / (de.w + 1e-6f);
    }

    float sum = 0.f;
#pragma unroll
    for (int j = 0; j < 16; ++j) sum += x[j];
    sum = red8(sum);
    float mu = sum * (1.0f / KD);
    float vs = 0.f;
#pragma unroll
    for (int j = 0; j < 16; ++j) { float dlt = x[j] - mu; vs = fmaf(dlt, dlt, vs); }
    vs = red8(vs);
    float rstd = rsqrtf(vs * (1.0f / KD) + LN_EPS);

    if (!valid) return;
    const float4* pg = (const float4*)(g + d0);
    const float4* pbe = (const float4*)(beta + d0);
    float4* op = (float4*)(out + (size_t)r * KD + d0);
#pragma unroll
    for (int q = 0; q < 4; ++q) {
        float4 gq = pg[q], bq = pbe[q];
        const float4 nf = *(const float4*)(&tile[rl][d0 + q * 4]);  // residual from LDS
        float4 o;
        {
            float ln = (x[q * 4 + 0] - mu) * rstd * gq.x + bq.x;
            o.x = nf.x + ln * sigmoidf_(ln);
        }
        {
            float ln = (x[q * 4 + 1] - mu) * rstd * gq.y + bq.y;
            o.y = nf.y + ln * sigmoidf_(ln);
        }
        {
            float ln = (x[q * 4 + 2] - mu) * rstd * gq.z + bq.z;
            o.z = nf.z + ln * sigmoidf_(ln);
        }
        {
            float ln = (x[q * 4 + 3] - mu) * rstd * gq.w + bq.w;
            o.w = nf.w + ln * sigmoidf_(ln);
        }
        op[q] = o;
    }
}

// ---------- launch ----------
extern "C" void kernel_launch(void* const* d_in, const int* in_sizes, int n_in,
                              void* d_out, int out_size, void* d_ws, size_t ws_size,
                              hipStream_t stream) {
    const float* node_feats = (const float*)d_in[0];
    const float* edge_feats = (const float*)d_in[1];
    const int* src = (const int*)d_in[2];
    const int* dst = (const int*)d_in[3];
    const float* W_src_gate = (const float*)d_in[4];
    const float* b_src_gate = (const float*)d_in[5];
    const float* W_dst_gate = (const float*)d_in[6];
    const float* b_dst_gate = (const float*)d_in[7];
    const float* W_edge_gate = (const float*)d_in[8];
    const float* b_edge_gate = (const float*)d_in[9];
    const float* W_src_update = (const float*)d_in[10];
    const float* b_src_update = (const float*)d_in[11];
    const float* W_dst_update = (const float*)d_in[12];
    const float* b_dst_update = (const float*)d_in[13];
    const float* g_nodes = (const float*)d_in[14];
    const float* beta_nodes = (const float*)d_in[15];
    const float* g_edges = (const float*)d_in[16];
    const float* beta_edges = (const float*)d_in[17];

    int N = in_sizes[0] / KD;
    int E = in_sizes[2];

    float* ws = (float*)d_ws;
    size_t nd = (size_t)N * KD;
    float* e_src = ws;            // [N,128]
    float* e_dst = e_src + nd;    // [N,128]
    float* Bh = e_dst + nd;       // [N,128]
    float* ssh = Bh + nd;         // [N,128] accum
    float* ssum = ssh + nd;       // [N,128] accum
    // total ws use: 5*N*128*4 bytes = ~128 MB

    float* out_nodes = (float*)d_out;
    float* out_edges = out_nodes + nd;

    hipMemsetAsync(ssh, 0, 2 * nd * sizeof(float), stream);

    int nodeBlocks = (N + ROWS - 1) / ROWS;
    int edgeBlocks = (E + ROWS - 1) / ROWS;

    node_gemm3<<<nodeBlocks, BT, 0, stream>>>(
        node_feats, W_src_gate, b_src_gate, W_dst_gate, b_dst_gate,
        W_dst_update, b_dst_update, e_src, e_dst, Bh, N);

    edge_fused<<<edgeBlocks, BT, 0, stream>>>(
        edge_feats, src, dst, W_edge_gate, b_edge_gate,
        e_src, e_dst, Bh, g_edges, beta_edges, ssh, ssum, out_edges, E);

    node_finalize<<<nodeBlocks, BT, 0, stream>>>(
        node_feats, W_src_update, b_src_update, ssh, ssum,
        g_nodes, beta_nodes, out_nodes, N);
}

// Round 7
// 4491.748 us; speedup vs baseline: 2.8148x; 2.8148x over previous
//
#include <hip/hip_runtime.h>
#include <math.h>

#define KD 128
#define ROWS 32      // rows (nodes or edges) per block
#define BT 256       // ROWS * 8 threads; 8 threads cover 128 cols (16 each)
#define LN_EPS 1e-5f
#define SCAN_T 1024

// ---------- helpers ----------

__device__ __forceinline__ float red8(float v) {
    v += __shfl_xor(v, 1);
    v += __shfl_xor(v, 2);
    v += __shfl_xor(v, 4);
    return v;
}

__device__ __forceinline__ float sigmoidf_(float x) {
    return 1.0f / (1.0f + __expf(-x));
}

__device__ __forceinline__ unsigned int f2bf(float f) {   // RNE float->bf16 bits
    unsigned int u = __float_as_uint(f);
    return (u + 0x7FFFu + ((u >> 16) & 1u)) >> 16;
}
__device__ __forceinline__ float bf2f(unsigned int b) {   // bf16 bits (low16) -> float
    return __uint_as_float(b << 16);
}

#define FMA16(XK, WA, WB, WC, WD)                                   \
    acc[0]  = fmaf(XK, WA.x, acc[0]);  acc[1]  = fmaf(XK, WA.y, acc[1]);  \
    acc[2]  = fmaf(XK, WA.z, acc[2]);  acc[3]  = fmaf(XK, WA.w, acc[3]);  \
    acc[4]  = fmaf(XK, WB.x, acc[4]);  acc[5]  = fmaf(XK, WB.y, acc[5]);  \
    acc[6]  = fmaf(XK, WB.z, acc[6]);  acc[7]  = fmaf(XK, WB.w, acc[7]);  \
    acc[8]  = fmaf(XK, WC.x, acc[8]);  acc[9]  = fmaf(XK, WC.y, acc[9]);  \
    acc[10] = fmaf(XK, WC.z, acc[10]); acc[11] = fmaf(XK, WC.w, acc[11]); \
    acc[12] = fmaf(XK, WD.x, acc[12]); acc[13] = fmaf(XK, WD.y, acc[13]); \
    acc[14] = fmaf(XK, WD.z, acc[14]); acc[15] = fmaf(XK, WD.w, acc[15]);

__device__ __forceinline__ void tile_gemm(const float (*tile)[KD + 4],
                                          const float* __restrict__ W,
                                          int rl, int d0, float acc[16]) {
#pragma unroll
    for (int j = 0; j < 16; ++j) acc[j] = 0.0f;
#pragma unroll 2
    for (int k4 = 0; k4 < KD / 4; ++k4) {
        float4 xk4 = *(const float4*)(&tile[rl][k4 * 4]);
        const float* Wr = W + (k4 * 4) * KD + d0;
        {
            float xk = xk4.x;
            const float4* wp = (const float4*)(Wr);
            float4 wa = wp[0], wb = wp[1], wc = wp[2], wd = wp[3];
            FMA16(xk, wa, wb, wc, wd);
        }
        {
            float xk = xk4.y;
            const float4* wp = (const float4*)(Wr + KD);
            float4 wa = wp[0], wb = wp[1], wc = wp[2], wd = wp[3];
            FMA16(xk, wa, wb, wc, wd);
        }
        {
            float xk = xk4.z;
            const float4* wp = (const float4*)(Wr + 2 * KD);
            float4 wa = wp[0], wb = wp[1], wc = wp[2], wd = wp[3];
            FMA16(xk, wa, wb, wc, wd);
        }
        {
            float xk = xk4.w;
            const float4* wp = (const float4*)(Wr + 3 * KD);
            float4 wa = wp[0], wb = wp[1], wc = wp[2], wd = wp[3];
            FMA16(xk, wa, wb, wc, wd);
        }
    }
}

__device__ __forceinline__ void stage_tile(const float* __restrict__ Xg, int rowBase,
                                           int nRows, float (*tile)[KD + 4], int t) {
    int r = t >> 3;
    int c = (t & 7) * 16;
    int gr = rowBase + r;
    float4 v0, v1, v2, v3;
    if (gr < nRows) {
        const float4* p = (const float4*)(Xg + (size_t)gr * KD + c);
        v0 = p[0]; v1 = p[1]; v2 = p[2]; v3 = p[3];
    } else {
        v0 = v1 = v2 = v3 = make_float4(0.f, 0.f, 0.f, 0.f);
    }
    float4* q = (float4*)(&tile[r][c]);
    q[0] = v0; q[1] = v1; q[2] = v2; q[3] = v3;
}

__device__ __forceinline__ void store_bias(float* __restrict__ O, const float* __restrict__ b,
                                           int gr, int d0, const float acc[16], int nRows) {
    if (gr >= nRows) return;
    const float4* bp = (const float4*)(b + d0);
    float4* op = (float4*)(O + (size_t)gr * KD + d0);
#pragma unroll
    for (int q = 0; q < 4; ++q) {
        float4 bb = bp[q];
        float4 o;
        o.x = acc[q * 4 + 0] + bb.x;
        o.y = acc[q * 4 + 1] + bb.y;
        o.z = acc[q * 4 + 2] + bb.z;
        o.w = acc[q * 4 + 3] + bb.w;
        op[q] = o;
    }
}

// ---------- kernel 1: three node GEMMs sharing one X tile ----------
__global__ void __launch_bounds__(BT)
node_gemm3(const float* __restrict__ X,
           const float* __restrict__ W0, const float* __restrict__ b0,
           const float* __restrict__ W1, const float* __restrict__ b1,
           const float* __restrict__ W2, const float* __restrict__ b2,
           float* __restrict__ O0, float* __restrict__ O1,
           float* __restrict__ O2, int N) {
    __shared__ float tile[ROWS][KD + 4];
    int t = threadIdx.x;
    int rowBase = blockIdx.x * ROWS;
    stage_tile(X, rowBase, N, tile, t);
    __syncthreads();
    int rl = t >> 3, d0 = (t & 7) * 16;
    int gr = rowBase + rl;
    float acc[16];
    tile_gemm(tile, W0, rl, d0, acc);
    store_bias(O0, b0, gr, d0, acc, N);
    tile_gemm(tile, W1, rl, d0, acc);
    store_bias(O1, b1, gr, d0, acc, N);
    tile_gemm(tile, W2, rl, d0, acc);
    store_bias(O2, b2, gr, d0, acc, N);
}

// ---------- CSR build ----------
__global__ void __launch_bounds__(256)
csr_count(const int* __restrict__ dst, int* __restrict__ deg, int E) {
    int e = blockIdx.x * 256 + threadIdx.x;
    if (e < E) atomicAdd(&deg[dst[e]], 1);
}

// one-block exclusive scan of deg[0..N) -> off[0..N], also copies to cur
__global__ void __launch_bounds__(SCAN_T)
csr_scan(const int* __restrict__ deg, int* __restrict__ off, int* __restrict__ cur,
         int N, int E) {
    __shared__ int partial[SCAN_T];
    int t = threadIdx.x;
    int chunk = (N + SCAN_T - 1) / SCAN_T;
    int lo = t * chunk, hi = min(lo + chunk, N);
    int s = 0;
    for (int i = lo; i < hi; ++i) s += deg[i];
    partial[t] = s;
    __syncthreads();
    // Hillis-Steele inclusive scan
    for (int d = 1; d < SCAN_T; d <<= 1) {
        int v = (t >= d) ? partial[t - d] : 0;
        __syncthreads();
        partial[t] += v;
        __syncthreads();
    }
    int run = (t == 0) ? 0 : partial[t - 1];   // exclusive base
    for (int i = lo; i < hi; ++i) {
        off[i] = run;
        cur[i] = run;
        run += deg[i];
    }
    if (t == 0) off[N] = E;
}

__global__ void __launch_bounds__(256)
csr_fill(const int* __restrict__ src, const int* __restrict__ dst,
         int* __restrict__ cur, int* __restrict__ csr_e, int* __restrict__ csr_s,
         int E) {
    int e = blockIdx.x * 256 + threadIdx.x;
    if (e < E) {
        int dd = dst[e];
        int p = atomicAdd(&cur[dd], 1);
        csr_e[p] = e;
        csr_s[p] = src[e];
    }
}

// ---------- kernel 2: fused edge pipeline (NO atomics) ----------
// m = EF@W + b + e_src[src] + e_dst[dst]; sigma = sigmoid(m) -> stored bf16
// y = EF + silu(LN(m)) written straight to output.
__global__ void __launch_bounds__(BT)
edge_fused2(const float* __restrict__ EF, const int* __restrict__ src,
            const int* __restrict__ dst,
            const float* __restrict__ W, const float* __restrict__ bW,
            const float* __restrict__ Esrc, const float* __restrict__ Edst,
            const float* __restrict__ g, const float* __restrict__ beta,
            unsigned short* __restrict__ sigma,
            float* __restrict__ yout, int E) {
    __shared__ float tile[ROWS][KD + 4];
    int t = threadIdx.x;
    int eBase = blockIdx.x * ROWS;
    stage_tile(EF, eBase, E, tile, t);
    __syncthreads();
    int rl = t >> 3, d0 = (t & 7) * 16;
    int e = eBase + rl;
    bool valid = e < E;

    float acc[16];
    tile_gemm(tile, W, rl, d0, acc);

    int s = 0, dd = 0;
    if (valid) { s = src[e]; dd = dst[e]; }

    const float4* ps = (const float4*)(Esrc + (size_t)s * KD + d0);
    const float4* pd = (const float4*)(Edst + (size_t)dd * KD + d0);
    const float4* pb = (const float4*)(bW + d0);
#pragma unroll
    for (int q = 0; q < 4; ++q) {
        float4 a = ps[q], bq = pd[q], c = pb[q];
        acc[q * 4 + 0] += a.x + bq.x + c.x;
        acc[q * 4 + 1] += a.y + bq.y + c.y;
        acc[q * 4 + 2] += a.z + bq.z + c.z;
        acc[q * 4 + 3] += a.w + bq.w + c.w;
    }

    if (valid) {
        // sigma -> bf16 packed, one 32 B store
        unsigned int w[8];
#pragma unroll
        for (int q = 0; q < 8; ++q) {
            unsigned int lo = f2bf(sigmoidf_(acc[2 * q]));
            unsigned int hi = f2bf(sigmoidf_(acc[2 * q + 1]));
            w[q] = lo | (hi << 16);
        }
        uint4* sp = (uint4*)(sigma + (size_t)e * KD + d0);
        sp[0] = make_uint4(w[0], w[1], w[2], w[3]);
        sp[1] = make_uint4(w[4], w[5], w[6], w[7]);
    }

    // LayerNorm of m (two-pass, in registers)
    float sum = 0.f;
#pragma unroll
    for (int j = 0; j < 16; ++j) sum += acc[j];
    sum = red8(sum);
    float mu = sum * (1.0f / KD);
    float vs = 0.f;
#pragma unroll
    for (int j = 0; j < 16; ++j) { float dlt = acc[j] - mu; vs = fmaf(dlt, dlt, vs); }
    vs = red8(vs);
    float rstd = rsqrtf(vs * (1.0f / KD) + LN_EPS);

    if (valid) {
        const float4* pg = (const float4*)(g + d0);
        const float4* pbe = (const float4*)(beta + d0);
        float4* op = (float4*)(yout + (size_t)e * KD + d0);
#pragma unroll
        for (int q = 0; q < 4; ++q) {
            float4 gq = pg[q], bq = pbe[q];
            const float4 efq = *(const float4*)(&tile[rl][d0 + q * 4]);
            float4 o;
            { float ln = (acc[q*4+0]-mu)*rstd*gq.x + bq.x; o.x = efq.x + ln*sigmoidf_(ln); }
            { float ln = (acc[q*4+1]-mu)*rstd*gq.y + bq.y; o.y = efq.y + ln*sigmoidf_(ln); }
            { float ln = (acc[q*4+2]-mu)*rstd*gq.z + bq.z; o.z = efq.z + ln*sigmoidf_(ln); }
            { float ln = (acc[q*4+3]-mu)*rstd*gq.w + bq.w; o.w = efq.w + ln*sigmoidf_(ln); }
            op[q] = o;
        }
    }
}

// ---------- kernel 3: node aggregate + finalize (no atomics) ----------
// num/den = sums over CSR in-edges; x = NF@W + b + num/(den+1e-6)
// out = NF + silu(LN(x))
__global__ void __launch_bounds__(BT)
node_aggfin(const float* __restrict__ NF,
            const float* __restrict__ W, const float* __restrict__ bW,
            const int* __restrict__ off, const int* __restrict__ csr_e,
            const int* __restrict__ csr_s,
            const unsigned short* __restrict__ sigma,
            const float* __restrict__ Bh,
            const float* __restrict__ g, const float* __restrict__ beta,
            float* __restrict__ out, int N) {
    __shared__ float tile[ROWS][KD + 4];
    int t = threadIdx.x;
    int rowBase = blockIdx.x * ROWS;
    stage_tile(NF, rowBase, N, tile, t);
    __syncthreads();
    int rl = t >> 3, d0 = (t & 7) * 16;
    int r = rowBase + rl;
    bool valid = r < N;

    float x[16];
    tile_gemm(tile, W, rl, d0, x);   // x = NF@W (bias added below)

    float num[16], den[16];
#pragma unroll
    for (int j = 0; j < 16; ++j) { num[j] = 0.f; den[j] = 0.f; }

    int beg = 0, end = 0;
    if (valid) { beg = off[r]; end = off[r + 1]; }
    for (int i = beg; i < end; ++i) {
        int e = csr_e[i];
        int s = csr_s[i];
        const uint4* sp = (const uint4*)(sigma + (size_t)e * KD + d0);
        uint4 sa = sp[0], sb = sp[1];
        const float4* bp = (const float4*)(Bh + (size_t)s * KD + d0);
        float4 b0 = bp[0], b1 = bp[1], b2 = bp[2], b3 = bp[3];
        float sv[16];
        sv[0]  = bf2f(sa.x & 0xffffu); sv[1]  = bf2f(sa.x >> 16);
        sv[2]  = bf2f(sa.y & 0xffffu); sv[3]  = bf2f(sa.y >> 16);
        sv[4]  = bf2f(sa.z & 0xffffu); sv[5]  = bf2f(sa.z >> 16);
        sv[6]  = bf2f(sa.w & 0xffffu); sv[7]  = bf2f(sa.w >> 16);
        sv[8]  = bf2f(sb.x & 0xffffu); sv[9]  = bf2f(sb.x >> 16);
        sv[10] = bf2f(sb.y & 0xffffu); sv[11] = bf2f(sb.y >> 16);
        sv[12] = bf2f(sb.z & 0xffffu); sv[13] = bf2f(sb.z >> 16);
        sv[14] = bf2f(sb.w & 0xffffu); sv[15] = bf2f(sb.w >> 16);
        float bh[16] = { b0.x, b0.y, b0.z, b0.w, b1.x, b1.y, b1.z, b1.w,
                         b2.x, b2.y, b2.z, b2.w, b3.x, b3.y, b3.z, b3.w };
#pragma unroll
        for (int j = 0; j < 16; ++j) {
            num[j] = fmaf(bh[j], sv[j], num[j]);
            den[j] += sv[j];
        }
    }

    const float4* pb = (const float4*)(bW + d0);
#pragma unroll
    for (int q = 0; q < 4; ++q) {
        float4 bb = pb[q];
        x[q * 4 + 0] += bb.x + num[q * 4 + 0] / (den[q * 4 + 0] + 1e-6f);
        x[q * 4 + 1] += bb.y + num[q * 4 + 1] / (den[q * 4 + 1] + 1e-6f);
        x[q * 4 + 2] += bb.z + num[q * 4 + 2] / (den[q * 4 + 2] + 1e-6f);
        x[q * 4 + 3] += bb.w + num[q * 4 + 3] / (den[q * 4 + 3] + 1e-6f);
    }

    float sum = 0.f;
#pragma unroll
    for (int j = 0; j < 16; ++j) sum += x[j];
    sum = red8(sum);
    float mu = sum * (1.0f / KD);
    float vs = 0.f;
#pragma unroll
    for (int j = 0; j < 16; ++j) { float dlt = x[j] - mu; vs = fmaf(dlt, dlt, vs); }
    vs = red8(vs);
    float rstd = rsqrtf(vs * (1.0f / KD) + LN_EPS);

    if (!valid) return;
    const float4* pg = (const float4*)(g + d0);
    const float4* pbe = (const float4*)(beta + d0);
    float4* op = (float4*)(out + (size_t)r * KD + d0);
#pragma unroll
    for (int q = 0; q < 4; ++q) {
        float4 gq = pg[q], bq = pbe[q];
        const float4 nf = *(const float4*)(&tile[rl][d0 + q * 4]);
        float4 o;
        { float ln = (x[q*4+0]-mu)*rstd*gq.x + bq.x; o.x = nf.x + ln*sigmoidf_(ln); }
        { float ln = (x[q*4+1]-mu)*rstd*gq.y + bq.y; o.y = nf.y + ln*sigmoidf_(ln); }
        { float ln = (x[q*4+2]-mu)*rstd*gq.z + bq.z; o.z = nf.z + ln*sigmoidf_(ln); }
        { float ln = (x[q*4+3]-mu)*rstd*gq.w + bq.w; o.w = nf.w + ln*sigmoidf_(ln); }
        op[q] = o;
    }
}

// ---------- launch ----------
extern "C" void kernel_launch(void* const* d_in, const int* in_sizes, int n_in,
                              void* d_out, int out_size, void* d_ws, size_t ws_size,
                              hipStream_t stream) {
    const float* node_feats = (const float*)d_in[0];
    const float* edge_feats = (const float*)d_in[1];
    const int* src = (const int*)d_in[2];
    const int* dst = (const int*)d_in[3];
    const float* W_src_gate = (const float*)d_in[4];
    const float* b_src_gate = (const float*)d_in[5];
    const float* W_dst_gate = (const float*)d_in[6];
    const float* b_dst_gate = (const float*)d_in[7];
    const float* W_edge_gate = (const float*)d_in[8];
    const float* b_edge_gate = (const float*)d_in[9];
    const float* W_src_update = (const float*)d_in[10];
    const float* b_src_update = (const float*)d_in[11];
    const float* W_dst_update = (const float*)d_in[12];
    const float* b_dst_update = (const float*)d_in[13];
    const float* g_nodes = (const float*)d_in[14];
    const float* beta_nodes = (const float*)d_in[15];
    const float* g_edges = (const float*)d_in[16];
    const float* beta_edges = (const float*)d_in[17];

    int N = in_sizes[0] / KD;
    int E = in_sizes[2];

    size_t nd = (size_t)N * KD;
    float* ws = (float*)d_ws;
    float* e_src = ws;                               // [N,128] f32
    float* e_dst = e_src + nd;                       // [N,128] f32
    float* Bh = e_dst + nd;                          // [N,128] f32
    unsigned short* sigma = (unsigned short*)(Bh + nd);  // [E,128] bf16
    int* deg = (int*)(sigma + (size_t)E * KD);       // [N]
    int* off = deg + N;                              // [N+1]
    int* cur = off + N + 1;                          // [N]
    int* csr_e = cur + N;                            // [E]
    int* csr_s = csr_e + E;                          // [E]
    // total ws: 3*25.6MB + 204.8MB + ~7MB ≈ 289 MB

    float* out_nodes = (float*)d_out;
    float* out_edges = out_nodes + nd;

    hipMemsetAsync(deg, 0, (size_t)N * sizeof(int), stream);

    int nodeBlocks = (N + ROWS - 1) / ROWS;
    int edgeBlocks = (E + ROWS - 1) / ROWS;
    int eThreads = (E + 255) / 256;

    node_gemm3<<<nodeBlocks, BT, 0, stream>>>(
        node_feats, W_src_gate, b_src_gate, W_dst_gate, b_dst_gate,
        W_dst_update, b_dst_update, e_src, e_dst, Bh, N);

    csr_count<<<eThreads, 256, 0, stream>>>(dst, deg, E);
    csr_scan<<<1, SCAN_T, 0, stream>>>(deg, off, cur, N, E);
    csr_fill<<<eThreads, 256, 0, stream>>>(src, dst, cur, csr_e, csr_s, E);

    edge_fused2<<<edgeBlocks, BT, 0, stream>>>(
        edge_feats, src, dst, W_edge_gate, b_edge_gate,
        e_src, e_dst, g_edges, beta_edges, sigma, out_edges, E);

    node_aggfin<<<nodeBlocks, BT, 0, stream>>>(
        node_feats, W_src_update, b_src_update, off, csr_e, csr_s,
        sigma, Bh, g_nodes, beta_nodes, out_nodes, N);
}